// Round 8
// baseline (746.746 us; speedup 1.0000x reference)
//
#include <hip/hip_runtime.h>
#include <math.h>

// Problem constants
#define B_   64
#define T_   256
#define W_   20
#define NP_  6
#define NT_  12
#define CC_  32      // CONV_CH
#define FD_  8       // FRAG_DIM
#define PR_  64      // PROJ

typedef float v2f __attribute__((ext_vector_type(2)));

// Pin a 2-register value into VGPRs (opaque def; blocks rematerialization.
// float4 form does NOT compile on gfx950; v2f proven in R7: VGPR 76 = 64
// pinned floats actually resident).
#define PIN2(x) asm volatile("" : "+v"(x))
// Wave-local LDS ordering: drain LDS ops only; no vmcnt, no barrier.
#define WAVE_SYNC() asm volatile("s_waitcnt lgkmcnt(0)" ::: "memory")

__device__ __forceinline__ float sigmoidf_(float x) {
    return 1.0f / (1.0f + __expf(-x));
}
__device__ __forceinline__ float tanhf_(float x) {
    x = fminf(fmaxf(x, -15.0f), 15.0f);
    float e = __expf(2.0f * x);
    return (e - 1.0f) / (e + 1.0f);
}

// -------------------------------------------------------------------------
// Kernel 1: encoders + fragility + projection + LSTM input-gate precompute.
// Only change this round: xg output layout is now gate-interleaved
// [b][t][unit][4] (i,f,g,o) so each lane writes ONE coalesced float4 and the
// LSTM reads one dwordx4 per step.
// -------------------------------------------------------------------------
__global__ __launch_bounds__(256, 3) void encoder_kernel(
    const float* __restrict__ pressure, const float* __restrict__ torque,
    const float* __restrict__ frag,
    const float* __restrict__ pw1, const float* __restrict__ pb1,
    const float* __restrict__ pw2, const float* __restrict__ pb2,
    const float* __restrict__ tw1, const float* __restrict__ tb1,
    const float* __restrict__ tw2, const float* __restrict__ tb2,
    const float* __restrict__ fw,  const float* __restrict__ fb,
    const float* __restrict__ prw, const float* __restrict__ prb,
    const float* __restrict__ Wih, const float* __restrict__ bih,
    const float* __restrict__ bhh,
    float* __restrict__ xg)             // (B,T,64units,4gates) output
{
    const int tid  = threadIdx.x;       // 0..255
    const int wv   = tid >> 6;          // wave 0..3
    const int lane = tid & 63;
    const int bt   = blockIdx.x * 4 + wv;   // window id
    const int b    = bt >> 8;
    const int  o   = lane & 31;
    const bool isp = lane < 32;

    __shared__ float w2lds[64 * 97];                 // 24832 B, shared by all waves
    __shared__ __align__(16) float xwin4[4][360];    // per-wave window
    __shared__ __align__(16) float h14[4][1280];     // per-wave conv1 out
    __shared__ __align__(16) float catb4[4][72];
    __shared__ __align__(16) float featsh4[4][64];

    float* xwin   = xwin4[wv];
    float* h1     = h14[wv];
    float* catb   = catb4[wv];
    float* featsh = featsh4[wv];

    // ---- stage conv2 weights once per block (coalesced, rows 96 -> 97) ----
    for (int idx = tid; idx < CC_ * 96; idx += 256) {
        int row = idx / 96, col = idx - row * 96;
        w2lds[row * 97 + col] = pw2[idx];
    }
    for (int idx = tid; idx < CC_ * 96; idx += 256) {
        int row = idx / 96, col = idx - row * 96;
        w2lds[(32 + row) * 97 + col] = tw2[idx];
    }

    // ---- conv1 weights in regs, zero-padded to uniform 12 input rows ----
    float w1r[36];
    {
        const float* w1 = isp ? (pw1 + o * (NP_ * 3)) : (tw1 + o * (NT_ * 3));
        const int n3 = (isp ? NP_ : NT_) * 3;
        #pragma unroll
        for (int k = 0; k < 36; ++k) w1r[k] = (k < n3) ? w1[k] : 0.0f;
    }
    const float bz1 = isp ? pb1[o] : tb1[o];
    const float bz2 = isp ? pb2[o] : tb2[o];

    // ---- stage own window, transposing [w][i] -> [i][w] ----
    const float* pin = pressure + (size_t)bt * (W_ * NP_);
    for (int idx = lane; idx < W_ * NP_; idx += 64) {
        int w = idx / NP_, i = idx - w * NP_;
        xwin[i * 20 + w] = pin[idx];
    }
    const float* tin = torque + (size_t)bt * (W_ * NT_);
    for (int idx = lane; idx < W_ * NT_; idx += 64) {
        int w = idx / NT_, i = idx - w * NT_;
        xwin[120 + i * 20 + w] = tin[idx];
    }
    if (lane < FD_) catb[64 + lane] = fmaxf(frag[b] * fw[lane] + fb[lane], 0.0f);
    WAVE_SYNC();    // xwin visible within the wave (no vmcnt drain)

    // ---- conv1 (valid, K=3): uniform 12-row loop, weights in regs ----
    {
        const float* xin = xwin + (isp ? 0 : 120);
        float acc[18];
        #pragma unroll
        for (int l = 0; l < 18; ++l) acc[l] = bz1;
        #pragma unroll
        for (int i = 0; i < 12; ++i) {
            float4 xr4[5];
            const float4* xrow = (const float4*)(xin + i * 20);
            #pragma unroll
            for (int q = 0; q < 5; ++q) xr4[q] = xrow[q];     // broadcast b128
            const float* xr = (const float*)xr4;
            const float wk0 = w1r[i * 3 + 0], wk1 = w1r[i * 3 + 1], wk2 = w1r[i * 3 + 2];
            #pragma unroll
            for (int l = 0; l < 18; ++l)
                acc[l] += xr[l] * wk0 + xr[l + 1] * wk1 + xr[l + 2] * wk2;
        }
        float* h1o = h1 + (isp ? 0 : 640) + o * 20;
        #pragma unroll
        for (int l = 0; l < 18; ++l) h1o[l] = fmaxf(acc[l], 0.0f);
    }
    __syncthreads();   // the ONE real barrier: w2lds (cross-wave) + h1 ready

    // ---- conv2 (32->32, K=3) + relu + mean; weights from shared LDS ----
    {
        const float* h1i   = h1 + (isp ? 0 : 640);
        const float* w2row = w2lds + lane * 97;   // lane-distinct, 2/bank = free
        float s[16];
        #pragma unroll
        for (int l = 0; l < 16; ++l) s[l] = bz2;
        #pragma unroll 4
        for (int i = 0; i < 32; ++i) {
            float4 hr4[5];
            const float4* hrow = (const float4*)(h1i + i * 20);
            #pragma unroll
            for (int q = 0; q < 5; ++q) hr4[q] = hrow[q];     // broadcast b128
            const float* hr = (const float*)hr4;
            const float wk0 = w2row[i * 3 + 0], wk1 = w2row[i * 3 + 1], wk2 = w2row[i * 3 + 2];
            #pragma unroll
            for (int l = 0; l < 16; ++l)
                s[l] += hr[l] * wk0 + hr[l + 1] * wk1 + hr[l + 2] * wk2;
        }
        float m = 0.0f;
        #pragma unroll
        for (int l = 0; l < 16; ++l) m += fmaxf(s[l], 0.0f);
        catb[lane] = m * 0.0625f;
    }
    WAVE_SYNC();    // catb visible within the wave

    // ---- projection 72 -> 64, relu ----
    {
        float acc = prb[lane];
        const float4* w4 = (const float4*)(prw + lane * 72);
        const float4* c4 = (const float4*)catb;
        #pragma unroll
        for (int q = 0; q < 18; ++q) {
            float4 w = w4[q], cv = c4[q];
            acc += w.x * cv.x + w.y * cv.y + w.z * cv.z + w.w * cv.w;
        }
        featsh[lane] = fmaxf(acc, 0.0f);
    }
    WAVE_SYNC();    // featsh visible within the wave

    // ---- xg = feat @ Wih.T + bih + bhh ; gate-interleaved float4 store ----
    {
        float4 fr[16];
        const float4* f4 = (const float4*)featsh;
        #pragma unroll
        for (int q = 0; q < 16; ++q) fr[q] = f4[q];
        float acc4[4];
        #pragma unroll
        for (int gi = 0; gi < 4; ++gi) {
            const int g = gi * 64 + lane;        // torch gate order i,f,g,o
            const float4* w4 = (const float4*)(Wih + (size_t)g * 64);
            float acc = bih[g] + bhh[g];
            #pragma unroll
            for (int q = 0; q < 16; ++q) {
                float4 w = w4[q];
                acc += w.x * fr[q].x + w.y * fr[q].y + w.z * fr[q].z + w.w * fr[q].w;
            }
            acc4[gi] = acc;
        }
        float4 v = {acc4[0], acc4[1], acc4[2], acc4[3]};
        float4* xgrow4 = (float4*)(xg + (size_t)bt * 256);
        xgrow4[lane] = v;                        // 16B/lane, fully coalesced
    }
}

// -------------------------------------------------------------------------
// Kernel 2: LSTM — SINGLE WAVE per batch element, ALL 256 weight floats
// pinned in VGPRs (128 x PIN2, the construct R7 proved holds: VGPR 76 with
// 64 floats -> expect ~300 here under the 512 budget of (64,1)).
// No barrier, no cross-wave exchange: step = ds_write h -> lgkmcnt ->
// 16 ds_read_b128 broadcast + 128 pk-FMA -> activations. xg read as ONE
// dwordx4/lane/step (gate-interleaved layout), 4-deep ring prefetch.
// -------------------------------------------------------------------------
__global__ __launch_bounds__(64, 1) void lstm_kernel(
    const float* __restrict__ xg,     // (B,T,64,4), bias already included
    const float* __restrict__ Whh,    // (256,64)
    float* __restrict__ hout,         // (B,T,64)
    float* __restrict__ dout)         // full output buffer
{
    const int b = blockIdx.x;
    const int j = threadIdx.x;        // hidden unit index

    __shared__ __align__(16) float hs[64];

    // 4 Whh rows for unit j (i,f,g,o): 256 floats = 128 v2f, all pinned
    v2f wi[32], wf[32], wg[32], wo[32];
    {
        const v2f* ri = (const v2f*)(Whh + (size_t)(j)       * 64);
        const v2f* rf = (const v2f*)(Whh + (size_t)(64  + j) * 64);
        const v2f* rg = (const v2f*)(Whh + (size_t)(128 + j) * 64);
        const v2f* ro = (const v2f*)(Whh + (size_t)(192 + j) * 64);
        #pragma unroll
        for (int q = 0; q < 32; ++q) { wi[q] = ri[q]; wf[q] = rf[q]; wg[q] = rg[q]; wo[q] = ro[q]; }
        #pragma unroll
        for (int q = 0; q < 32; ++q) { PIN2(wi[q]); PIN2(wf[q]); PIN2(wg[q]); PIN2(wo[q]); }
    }

    const float4* xq = (const float4*)(xg + (size_t)b * T_ * 256) + j; // stride 64 float4/step
    float* hrow = hout + (size_t)b * T_ * 64;

    float c = 0.0f;
    hs[j] = 0.0f;
    WAVE_SYNC();

    // 4-deep ring prefetch of the per-step float4 (i,f,g,o)
    float4 x0 = xq[0], x1 = xq[64], x2 = xq[128], x3 = xq[192];

    float h = 0.0f;
    #pragma unroll 4
    for (int t = 0; t < T_; ++t) {
        const int tp = (t + 4 < T_) ? (t + 4) : (T_ - 1);
        float4 xf = xq[tp * 64];                 // in flight through the step

        v2f Ai = {x0.x, 0.0f}, Af = {x0.y, 0.0f}, Ag = {x0.z, 0.0f}, Ao = {x0.w, 0.0f};
        const float4* h4 = (const float4*)hs;
        #pragma unroll
        for (int q = 0; q < 16; ++q) {
            float4 hv4 = h4[q];                  // broadcast b128, conflict-free
            v2f lo = {hv4.x, hv4.y}, hi = {hv4.z, hv4.w};
            Ai += wi[2*q] * lo + wi[2*q+1] * hi;
            Af += wf[2*q] * lo + wf[2*q+1] * hi;
            Ag += wg[2*q] * lo + wg[2*q+1] * hi;
            Ao += wo[2*q] * lo + wo[2*q+1] * hi;
        }

        const float I = sigmoidf_(Ai.x + Ai.y);
        const float F = sigmoidf_(Af.x + Af.y);
        const float G = tanhf_(Ag.x + Ag.y);
        const float O = sigmoidf_(Ao.x + Ao.y);
        c = F * c + I * G;
        h = O * tanhf_(c);

        hs[j] = h;
        WAVE_SYNC();                  // lgkmcnt only; vmem stays in flight
        hrow[t * 64 + j] = h;         // coalesced store, never drained in-loop

        x0 = x1; x1 = x2; x2 = x3; x3 = xf;
    }

    dout[B_ * T_ * 4 + b * 64 + j]           = h;   // hT
    dout[B_ * T_ * 4 + B_ * 64 + b * 64 + j] = c;   // cT
}

// -------------------------------------------------------------------------
// Kernel 3: head (unchanged).
// -------------------------------------------------------------------------
__global__ __launch_bounds__(256) void head_kernel(
    const float* __restrict__ hout, const float* __restrict__ hw,
    const float* __restrict__ hb, float* __restrict__ out)
{
    const int blk = blockIdx.x;
    const int tid = threadIdx.x;

    __shared__ __align__(16) float hsh[64 * 68];
    __shared__ __align__(16) float wsh[256];
    __shared__ float bsh[4];

    const float4* s4 = (const float4*)(hout + (size_t)blk * 64 * 64);
    float4* d4 = (float4*)hsh;
    for (int q = tid; q < 1024; q += 256) {
        int row = q >> 4, col = q & 15;
        d4[row * 17 + col] = s4[q];
    }
    if (tid < 64) ((float4*)wsh)[tid] = ((const float4*)hw)[tid];
    if (tid < 4)  bsh[tid] = hb[tid];
    __syncthreads();

    const int r = tid >> 2, m = tid & 3;
    const float4* hv = (const float4*)(hsh + r * 68);
    const float4* wv = (const float4*)(wsh + m * 64);
    float acc = bsh[m];
    #pragma unroll
    for (int q = 0; q < 16; ++q) {
        float4 a = hv[q], w = wv[q];
        acc += a.x * w.x + a.y * w.y + a.z * w.z + a.w * w.w;
    }
    out[(size_t)blk * 256 + tid] = sigmoidf_(acc);
}

extern "C" void kernel_launch(void* const* d_in, const int* in_sizes, int n_in,
                              void* d_out, int out_size, void* d_ws, size_t ws_size,
                              hipStream_t stream) {
    const float* pressure = (const float*)d_in[0];
    const float* torque   = (const float*)d_in[1];
    const float* frag     = (const float*)d_in[2];
    const float* pw1 = (const float*)d_in[3];
    const float* pb1 = (const float*)d_in[4];
    const float* pw2 = (const float*)d_in[5];
    const float* pb2 = (const float*)d_in[6];
    const float* tw1 = (const float*)d_in[7];
    const float* tb1 = (const float*)d_in[8];
    const float* tw2 = (const float*)d_in[9];
    const float* tb2 = (const float*)d_in[10];
    const float* fw  = (const float*)d_in[11];
    const float* fb  = (const float*)d_in[12];
    const float* prw = (const float*)d_in[13];
    const float* prb = (const float*)d_in[14];
    const float* Wih = (const float*)d_in[15];
    const float* Whh = (const float*)d_in[16];
    const float* bih = (const float*)d_in[17];
    const float* bhh = (const float*)d_in[18];
    const float* hw  = (const float*)d_in[19];
    const float* hb  = (const float*)d_in[20];

    float* out = (float*)d_out;

    // workspace: xg (B*T*256 f32 = 16 MB, gate-interleaved) | hout (4 MB)
    float* xg   = (float*)d_ws;
    float* hout = xg + (size_t)B_ * T_ * 256;

    encoder_kernel<<<B_ * T_ / 4, 256, 0, stream>>>(
        pressure, torque, frag,
        pw1, pb1, pw2, pb2, tw1, tb1, tw2, tb2,
        fw, fb, prw, prb, Wih, bih, bhh, xg);

    lstm_kernel<<<B_, 64, 0, stream>>>(xg, Whh, hout, out);

    head_kernel<<<B_ * T_ / 64, 256, 0, stream>>>(hout, hw, hb, out);
}

// Round 9
// 486.507 us; speedup vs baseline: 1.5349x; 1.5349x over previous
//
#include <hip/hip_runtime.h>
#include <math.h>

// Problem constants
#define B_   64
#define T_   256
#define W_   20
#define NP_  6
#define NT_  12
#define CC_  32      // CONV_CH
#define FD_  8       // FRAG_DIM
#define PR_  64      // PROJ

typedef float v2f __attribute__((ext_vector_type(2)));
typedef _Float16 half2_t __attribute__((ext_vector_type(2)));

// Pin a single 32-bit value into a VGPR (opaque def; blocks remat/spill-sink).
#define PINU(x) asm volatile("" : "+v"(x))
// Wave-local LDS ordering: drain LDS ops only; no vmcnt, no barrier.
#define WAVE_SYNC() asm volatile("s_waitcnt lgkmcnt(0)" ::: "memory")

#define H2(u) __builtin_bit_cast(half2_t, (u))

__device__ __forceinline__ float sigmoidf_(float x) {
    return 1.0f / (1.0f + __expf(-x));
}
__device__ __forceinline__ float tanhf_(float x) {
    x = fminf(fmaxf(x, -15.0f), 15.0f);
    float e = __expf(2.0f * x);
    return (e - 1.0f) / (e + 1.0f);
}

// -------------------------------------------------------------------------
// Kernel 1: encoders + fragility + projection + LSTM input-gate precompute.
// UNCHANGED from R8 (xg gate-interleaved [b][t][unit][4]); rewrite pending
// once the LSTM stops dominating.
// -------------------------------------------------------------------------
__global__ __launch_bounds__(256, 3) void encoder_kernel(
    const float* __restrict__ pressure, const float* __restrict__ torque,
    const float* __restrict__ frag,
    const float* __restrict__ pw1, const float* __restrict__ pb1,
    const float* __restrict__ pw2, const float* __restrict__ pb2,
    const float* __restrict__ tw1, const float* __restrict__ tb1,
    const float* __restrict__ tw2, const float* __restrict__ tb2,
    const float* __restrict__ fw,  const float* __restrict__ fb,
    const float* __restrict__ prw, const float* __restrict__ prb,
    const float* __restrict__ Wih, const float* __restrict__ bih,
    const float* __restrict__ bhh,
    float* __restrict__ xg)             // (B,T,64units,4gates) output
{
    const int tid  = threadIdx.x;       // 0..255
    const int wv   = tid >> 6;          // wave 0..3
    const int lane = tid & 63;
    const int bt   = blockIdx.x * 4 + wv;   // window id
    const int b    = bt >> 8;
    const int  o   = lane & 31;
    const bool isp = lane < 32;

    __shared__ float w2lds[64 * 97];                 // 24832 B, shared by all waves
    __shared__ __align__(16) float xwin4[4][360];    // per-wave window
    __shared__ __align__(16) float h14[4][1280];     // per-wave conv1 out
    __shared__ __align__(16) float catb4[4][72];
    __shared__ __align__(16) float featsh4[4][64];

    float* xwin   = xwin4[wv];
    float* h1     = h14[wv];
    float* catb   = catb4[wv];
    float* featsh = featsh4[wv];

    // ---- stage conv2 weights once per block (coalesced, rows 96 -> 97) ----
    for (int idx = tid; idx < CC_ * 96; idx += 256) {
        int row = idx / 96, col = idx - row * 96;
        w2lds[row * 97 + col] = pw2[idx];
    }
    for (int idx = tid; idx < CC_ * 96; idx += 256) {
        int row = idx / 96, col = idx - row * 96;
        w2lds[(32 + row) * 97 + col] = tw2[idx];
    }

    // ---- conv1 weights in regs, zero-padded to uniform 12 input rows ----
    float w1r[36];
    {
        const float* w1 = isp ? (pw1 + o * (NP_ * 3)) : (tw1 + o * (NT_ * 3));
        const int n3 = (isp ? NP_ : NT_) * 3;
        #pragma unroll
        for (int k = 0; k < 36; ++k) w1r[k] = (k < n3) ? w1[k] : 0.0f;
    }
    const float bz1 = isp ? pb1[o] : tb1[o];
    const float bz2 = isp ? pb2[o] : tb2[o];

    // ---- stage own window, transposing [w][i] -> [i][w] ----
    const float* pin = pressure + (size_t)bt * (W_ * NP_);
    for (int idx = lane; idx < W_ * NP_; idx += 64) {
        int w = idx / NP_, i = idx - w * NP_;
        xwin[i * 20 + w] = pin[idx];
    }
    const float* tin = torque + (size_t)bt * (W_ * NT_);
    for (int idx = lane; idx < W_ * NT_; idx += 64) {
        int w = idx / NT_, i = idx - w * NT_;
        xwin[120 + i * 20 + w] = tin[idx];
    }
    if (lane < FD_) catb[64 + lane] = fmaxf(frag[b] * fw[lane] + fb[lane], 0.0f);
    WAVE_SYNC();    // xwin visible within the wave (no vmcnt drain)

    // ---- conv1 (valid, K=3): uniform 12-row loop, weights in regs ----
    {
        const float* xin = xwin + (isp ? 0 : 120);
        float acc[18];
        #pragma unroll
        for (int l = 0; l < 18; ++l) acc[l] = bz1;
        #pragma unroll
        for (int i = 0; i < 12; ++i) {
            float4 xr4[5];
            const float4* xrow = (const float4*)(xin + i * 20);
            #pragma unroll
            for (int q = 0; q < 5; ++q) xr4[q] = xrow[q];     // broadcast b128
            const float* xr = (const float*)xr4;
            const float wk0 = w1r[i * 3 + 0], wk1 = w1r[i * 3 + 1], wk2 = w1r[i * 3 + 2];
            #pragma unroll
            for (int l = 0; l < 18; ++l)
                acc[l] += xr[l] * wk0 + xr[l + 1] * wk1 + xr[l + 2] * wk2;
        }
        float* h1o = h1 + (isp ? 0 : 640) + o * 20;
        #pragma unroll
        for (int l = 0; l < 18; ++l) h1o[l] = fmaxf(acc[l], 0.0f);
    }
    __syncthreads();   // the ONE real barrier: w2lds (cross-wave) + h1 ready

    // ---- conv2 (32->32, K=3) + relu + mean; weights from shared LDS ----
    {
        const float* h1i   = h1 + (isp ? 0 : 640);
        const float* w2row = w2lds + lane * 97;   // lane-distinct, 2/bank = free
        float s[16];
        #pragma unroll
        for (int l = 0; l < 16; ++l) s[l] = bz2;
        #pragma unroll 4
        for (int i = 0; i < 32; ++i) {
            float4 hr4[5];
            const float4* hrow = (const float4*)(h1i + i * 20);
            #pragma unroll
            for (int q = 0; q < 5; ++q) hr4[q] = hrow[q];     // broadcast b128
            const float* hr = (const float*)hr4;
            const float wk0 = w2row[i * 3 + 0], wk1 = w2row[i * 3 + 1], wk2 = w2row[i * 3 + 2];
            #pragma unroll
            for (int l = 0; l < 16; ++l)
                s[l] += hr[l] * wk0 + hr[l + 1] * wk1 + hr[l + 2] * wk2;
        }
        float m = 0.0f;
        #pragma unroll
        for (int l = 0; l < 16; ++l) m += fmaxf(s[l], 0.0f);
        catb[lane] = m * 0.0625f;
    }
    WAVE_SYNC();    // catb visible within the wave

    // ---- projection 72 -> 64, relu ----
    {
        float acc = prb[lane];
        const float4* w4 = (const float4*)(prw + lane * 72);
        const float4* c4 = (const float4*)catb;
        #pragma unroll
        for (int q = 0; q < 18; ++q) {
            float4 w = w4[q], cv = c4[q];
            acc += w.x * cv.x + w.y * cv.y + w.z * cv.z + w.w * cv.w;
        }
        featsh[lane] = fmaxf(acc, 0.0f);
    }
    WAVE_SYNC();    // featsh visible within the wave

    // ---- xg = feat @ Wih.T + bih + bhh ; gate-interleaved float4 store ----
    {
        float4 fr[16];
        const float4* f4 = (const float4*)featsh;
        #pragma unroll
        for (int q = 0; q < 16; ++q) fr[q] = f4[q];
        float acc4[4];
        #pragma unroll
        for (int gi = 0; gi < 4; ++gi) {
            const int g = gi * 64 + lane;        // torch gate order i,f,g,o
            const float4* w4 = (const float4*)(Wih + (size_t)g * 64);
            float acc = bih[g] + bhh[g];
            #pragma unroll
            for (int q = 0; q < 16; ++q) {
                float4 w = w4[q];
                acc += w.x * fr[q].x + w.y * fr[q].y + w.z * fr[q].z + w.w * fr[q].w;
            }
            acc4[gi] = acc;
        }
        float4 v = {acc4[0], acc4[1], acc4[2], acc4[3]};
        float4* xgrow4 = (float4*)(xg + (size_t)bt * 256);
        xgrow4[lane] = v;                        // 16B/lane, fully coalesced
    }
}

// -------------------------------------------------------------------------
// Kernel 2: LSTM — SINGLE WAVE per element, f16 weights + v_dot2_f32_f16.
// R8 proved the VGPR cap is 256 (not 512): 256 f32 weights/lane spilled
// (VGPR_Count=256, WRITE_SIZE +2.6MB scratch). Fix: Whh rows as f16 pairs:
// 128 packed uints = 128 VGPRs, pinned -> fits with ~60 working regs.
// Matvec: 128 fdot2 (2 MACs each, f32 accumulate), 4 interleaved chains.
// No barrier, no cross-wave exchange; h round-trips LDS as f16.
// -------------------------------------------------------------------------
__global__ __launch_bounds__(64, 1) void lstm_kernel(
    const float* __restrict__ xg,     // (B,T,64,4), bias already included
    const float* __restrict__ Whh,    // (256,64)
    float* __restrict__ hout,         // (B,T,64)
    float* __restrict__ dout)         // full output buffer
{
    const int b = blockIdx.x;
    const int j = threadIdx.x;        // hidden unit index

    __shared__ __align__(16) _Float16 hs[64];    // h state in f16 (128 B)

    // 4 Whh rows for unit j (i,f,g,o) as f16 pairs: 4 x 32 uints, pinned
    unsigned wi[32], wf[32], wg[32], wo[32];
    {
        const v2f* ri = (const v2f*)(Whh + (size_t)(j)       * 64);
        const v2f* rf = (const v2f*)(Whh + (size_t)(64  + j) * 64);
        const v2f* rg = (const v2f*)(Whh + (size_t)(128 + j) * 64);
        const v2f* ro = (const v2f*)(Whh + (size_t)(192 + j) * 64);
        #pragma unroll
        for (int q = 0; q < 32; ++q) {
            union { _Float16 h[2]; unsigned u; } cv;
            v2f w;
            w = ri[q]; cv.h[0] = (_Float16)w.x; cv.h[1] = (_Float16)w.y; wi[q] = cv.u;
            w = rf[q]; cv.h[0] = (_Float16)w.x; cv.h[1] = (_Float16)w.y; wf[q] = cv.u;
            w = rg[q]; cv.h[0] = (_Float16)w.x; cv.h[1] = (_Float16)w.y; wg[q] = cv.u;
            w = ro[q]; cv.h[0] = (_Float16)w.x; cv.h[1] = (_Float16)w.y; wo[q] = cv.u;
        }
        #pragma unroll
        for (int q = 0; q < 32; ++q) { PINU(wi[q]); PINU(wf[q]); PINU(wg[q]); PINU(wo[q]); }
    }

    const float4* xq = (const float4*)(xg + (size_t)b * T_ * 256) + j; // 1 float4/step
    float* hrow = hout + (size_t)b * T_ * 64;

    float c = 0.0f;
    float h = 0.0f;
    hs[j] = (_Float16)0.0f;
    WAVE_SYNC();

    // 2-deep xg prefetch (16B/lane/step)
    float4 x0 = xq[0], x1 = xq[64];

    for (int t = 0; t < T_; ++t) {
        const int tp = (t + 2 < T_) ? (t + 2) : (T_ - 1);
        float4 xf = xq[tp * 64];                 // stays in flight through the step

        // h broadcast: 64 halfs = 128 B = 8 x b128 reads, conflict-free
        uint4 hb[8];
        const uint4* hp = (const uint4*)hs;
        #pragma unroll
        for (int q = 0; q < 8; ++q) hb[q] = hp[q];
        const unsigned* hu = (const unsigned*)hb;

        float ai = x0.x, af = x0.y, ag = x0.z, ao = x0.w;
        #pragma unroll
        for (int q = 0; q < 32; ++q) {
            half2_t hq = H2(hu[q]);
            ai = __builtin_amdgcn_fdot2(H2(wi[q]), hq, ai, false);
            af = __builtin_amdgcn_fdot2(H2(wf[q]), hq, af, false);
            ag = __builtin_amdgcn_fdot2(H2(wg[q]), hq, ag, false);
            ao = __builtin_amdgcn_fdot2(H2(wo[q]), hq, ao, false);
        }

        const float I = sigmoidf_(ai);
        const float F = sigmoidf_(af);
        const float G = tanhf_(ag);
        const float O = sigmoidf_(ao);
        c = F * c + I * G;
        h = O * tanhf_(c);

        hs[j] = (_Float16)h;          // ds_write_b16
        WAVE_SYNC();                  // lgkmcnt only; vmem stays in flight
        hrow[t * 64 + j] = h;         // f32 coalesced store, never drained in-loop

        x0 = x1; x1 = xf;
    }

    dout[B_ * T_ * 4 + b * 64 + j]           = h;   // hT
    dout[B_ * T_ * 4 + B_ * 64 + b * 64 + j] = c;   // cT
}

// -------------------------------------------------------------------------
// Kernel 3: head (unchanged).
// -------------------------------------------------------------------------
__global__ __launch_bounds__(256) void head_kernel(
    const float* __restrict__ hout, const float* __restrict__ hw,
    const float* __restrict__ hb, float* __restrict__ out)
{
    const int blk = blockIdx.x;
    const int tid = threadIdx.x;

    __shared__ __align__(16) float hsh[64 * 68];
    __shared__ __align__(16) float wsh[256];
    __shared__ float bsh[4];

    const float4* s4 = (const float4*)(hout + (size_t)blk * 64 * 64);
    float4* d4 = (float4*)hsh;
    for (int q = tid; q < 1024; q += 256) {
        int row = q >> 4, col = q & 15;
        d4[row * 17 + col] = s4[q];
    }
    if (tid < 64) ((float4*)wsh)[tid] = ((const float4*)hw)[tid];
    if (tid < 4)  bsh[tid] = hb[tid];
    __syncthreads();

    const int r = tid >> 2, m = tid & 3;
    const float4* hv = (const float4*)(hsh + r * 68);
    const float4* wv = (const float4*)(wsh + m * 64);
    float acc = bsh[m];
    #pragma unroll
    for (int q = 0; q < 16; ++q) {
        float4 a = hv[q], w = wv[q];
        acc += a.x * w.x + a.y * w.y + a.z * w.z + a.w * w.w;
    }
    out[(size_t)blk * 256 + tid] = sigmoidf_(acc);
}

extern "C" void kernel_launch(void* const* d_in, const int* in_sizes, int n_in,
                              void* d_out, int out_size, void* d_ws, size_t ws_size,
                              hipStream_t stream) {
    const float* pressure = (const float*)d_in[0];
    const float* torque   = (const float*)d_in[1];
    const float* frag     = (const float*)d_in[2];
    const float* pw1 = (const float*)d_in[3];
    const float* pb1 = (const float*)d_in[4];
    const float* pw2 = (const float*)d_in[5];
    const float* pb2 = (const float*)d_in[6];
    const float* tw1 = (const float*)d_in[7];
    const float* tb1 = (const float*)d_in[8];
    const float* tw2 = (const float*)d_in[9];
    const float* tb2 = (const float*)d_in[10];
    const float* fw  = (const float*)d_in[11];
    const float* fb  = (const float*)d_in[12];
    const float* prw = (const float*)d_in[13];
    const float* prb = (const float*)d_in[14];
    const float* Wih = (const float*)d_in[15];
    const float* Whh = (const float*)d_in[16];
    const float* bih = (const float*)d_in[17];
    const float* bhh = (const float*)d_in[18];
    const float* hw  = (const float*)d_in[19];
    const float* hb  = (const float*)d_in[20];

    float* out = (float*)d_out;

    // workspace: xg (B*T*256 f32 = 16 MB, gate-interleaved) | hout (4 MB)
    float* xg   = (float*)d_ws;
    float* hout = xg + (size_t)B_ * T_ * 256;

    encoder_kernel<<<B_ * T_ / 4, 256, 0, stream>>>(
        pressure, torque, frag,
        pw1, pb1, pw2, pb2, tw1, tb1, tw2, tb2,
        fw, fb, prw, prb, Wih, bih, bhh, xg);

    lstm_kernel<<<B_, 64, 0, stream>>>(xg, Whh, hout, out);

    head_kernel<<<B_ * T_ / 64, 256, 0, stream>>>(hout, hw, hb, out);
}

// Round 10
// 450.739 us; speedup vs baseline: 1.6567x; 1.0794x over previous
//
#include <hip/hip_runtime.h>
#include <math.h>

// Problem constants
#define B_   64
#define T_   256
#define W_   20
#define NP_  6
#define NT_  12
#define CC_  32      // CONV_CH
#define FD_  8       // FRAG_DIM
#define PR_  64      // PROJ

typedef float v2f __attribute__((ext_vector_type(2)));
typedef _Float16 half2_t __attribute__((ext_vector_type(2)));

// Pin a single 32-bit value into a VGPR (opaque def; blocks remat/spill-sink).
#define PINU(x) asm volatile("" : "+v"(x))
// Wave-local LDS ordering: drain LDS ops only; no vmcnt, no barrier.
#define WAVE_SYNC() asm volatile("s_waitcnt lgkmcnt(0)" ::: "memory")

#define H2(u) __builtin_bit_cast(half2_t, (u))

__device__ __forceinline__ unsigned packh2(float a, float b) {
    union { _Float16 h[2]; unsigned u; } cv;
    cv.h[0] = (_Float16)a; cv.h[1] = (_Float16)b;
    return cv.u;
}

__device__ __forceinline__ float sigmoidf_(float x) {
    return 1.0f / (1.0f + __expf(-x));
}
__device__ __forceinline__ float tanhf_(float x) {
    x = fminf(fmaxf(x, -15.0f), 15.0f);
    float e = __expf(2.0f * x);
    return (e - 1.0f) / (e + 1.0f);
}

// -------------------------------------------------------------------------
// Kernel 1: encoders + projection + LSTM input-gate precompute.
// THIS ROUND: f16 channel-pair packing + v_dot2_f32_f16 for both convs.
//  - LDS/block 53248 -> 28800 B => 5 blocks/CU = 20 waves (was 3/12).
//  - conv VALU halved (dot2 = 2 MACs/inst).
//  - xg store reverted to gate-blocked scalar (R9's interleaved float4 store
//    caused 4x WRITE_SIZE via partial-sector RMW writebacks).
// Data layout: channel PAIRS packed in one uint (lo=ch 2m, hi=ch 2m+1):
//   out[o][l] = sum_m sum_k dot2( wp[o][m][k], xp[m][l+k] )
// -------------------------------------------------------------------------
__global__ __launch_bounds__(256, 5) void encoder_kernel(
    const float* __restrict__ pressure, const float* __restrict__ torque,
    const float* __restrict__ frag,
    const float* __restrict__ pw1, const float* __restrict__ pb1,
    const float* __restrict__ pw2, const float* __restrict__ pb2,
    const float* __restrict__ tw1, const float* __restrict__ tb1,
    const float* __restrict__ tw2, const float* __restrict__ tb2,
    const float* __restrict__ fw,  const float* __restrict__ fb,
    const float* __restrict__ prw, const float* __restrict__ prb,
    const float* __restrict__ Wih, const float* __restrict__ bih,
    const float* __restrict__ bhh,
    float* __restrict__ xg)             // (B,T,4gates,64units) gate-blocked
{
    const int tid  = threadIdx.x;       // 0..255
    const int wv   = tid >> 6;          // wave 0..3
    const int lane = tid & 63;
    const int bt   = blockIdx.x * 4 + wv;   // window id
    const int b    = bt >> 8;
    const int  o   = lane & 31;
    const bool isp = lane < 32;
    const int  s   = isp ? 0 : 1;       // stream: 0=pressure, 1=torque

    __shared__ unsigned w2p[64 * 49];                    // 12544 B packed conv2 wts [outch][m*3+k]
    __shared__ __align__(16) unsigned xwp[4][2][120];    //  3840 B [wave][stream][pair*20+pos]
    __shared__ __align__(16) unsigned h1p[4][2][320];    // 10240 B [wave][stream][pair*20+pos]
    __shared__ __align__(16) float catb4[4][72];         //  1152 B pf|tf|ff
    __shared__ __align__(16) float featsh4[4][64];       //  1024 B

    float* catb   = catb4[wv];
    float* featsh = featsh4[wv];

    // ---- stage conv2 weights once per block, packed f16 pairs ----
    // row r (=lane space: 0..31 pressure outch, 32..63 torque outch), col c=m*3+k
    for (int idx = tid; idx < 64 * 48; idx += 256) {
        int r = idx / 48, c = idx - r * 48;
        int m = c / 3, k = c - m * 3;
        const float* src = (r < 32) ? (pw2 + r * 96) : (tw2 + (r - 32) * 96);
        w2p[r * 49 + c] = packh2(src[(2 * m) * 3 + k], src[(2 * m + 1) * 3 + k]);
    }

    // ---- zero + stage own window as packed f16 pairs (transposed) ----
    {
        unsigned* xz = &xwp[wv][0][0];
        #pragma unroll
        for (int idx = lane; idx < 240; idx += 64) xz[idx] = 0;   // pads pressure rows 3..5
    }
    const float* pin = pressure + (size_t)bt * (W_ * NP_);
    for (int idx = lane; idx < W_ * NP_; idx += 64) {
        int w = idx / NP_, i = idx - w * NP_;
        ((_Float16*)&xwp[wv][0][(i >> 1) * 20 + w])[i & 1] = (_Float16)pin[idx];
    }
    const float* tin = torque + (size_t)bt * (W_ * NT_);
    for (int idx = lane; idx < W_ * NT_; idx += 64) {
        int w = idx / NT_, i = idx - w * NT_;
        ((_Float16*)&xwp[wv][1][(i >> 1) * 20 + w])[i & 1] = (_Float16)tin[idx];
    }
    if (lane < FD_) catb[64 + lane] = fmaxf(frag[b] * fw[lane] + fb[lane], 0.0f);

    // ---- conv1 weights: packed f16 pairs in regs, zero-padded to 6 pairs ----
    unsigned w1p[18];
    {
        const float* w1 = isp ? (pw1 + o * (NP_ * 3)) : (tw1 + o * (NT_ * 3));
        const int npr = isp ? 3 : 6;    // channel pairs
        #pragma unroll
        for (int m = 0; m < 6; ++m)
            #pragma unroll
            for (int k = 0; k < 3; ++k)
                w1p[m * 3 + k] = (m < npr)
                    ? packh2(w1[(2 * m) * 3 + k], w1[(2 * m + 1) * 3 + k])
                    : 0u;
    }
    const float bz1 = isp ? pb1[o] : tb1[o];
    const float bz2 = isp ? pb2[o] : tb2[o];
    WAVE_SYNC();    // xwp visible within the wave

    // ---- conv1: 6 pair-rows x 3 taps x 18 pos, dot2 f16 -> f32 acc ----
    {
        const unsigned* xr = &xwp[wv][s][0];
        float acc[18];
        #pragma unroll
        for (int l = 0; l < 18; ++l) acc[l] = bz1;
        #pragma unroll
        for (int m = 0; m < 6; ++m) {
            uint4 r4[5];
            const uint4* rp = (const uint4*)(xr + m * 20);
            #pragma unroll
            for (int q = 0; q < 5; ++q) r4[q] = rp[q];        // broadcast b128
            const unsigned* rw = (const unsigned*)r4;
            const half2_t wk0 = H2(w1p[m * 3]), wk1 = H2(w1p[m * 3 + 1]), wk2 = H2(w1p[m * 3 + 2]);
            #pragma unroll
            for (int l = 0; l < 18; ++l) {
                float a = acc[l];
                a = __builtin_amdgcn_fdot2(wk0, H2(rw[l]),     a, false);
                a = __builtin_amdgcn_fdot2(wk1, H2(rw[l + 1]), a, false);
                a = __builtin_amdgcn_fdot2(wk2, H2(rw[l + 2]), a, false);
                acc[l] = a;
            }
        }
        // relu + write h1 packed: lane o -> pair o>>1, half o&1
        #pragma unroll
        for (int l = 0; l < 18; ++l)
            ((_Float16*)&h1p[wv][s][(o >> 1) * 20 + l])[o & 1] = (_Float16)fmaxf(acc[l], 0.0f);
    }
    __syncthreads();   // the ONE real barrier: w2p (cross-wave) + h1p ready

    // ---- conv2: 16 pair-rows x 3 taps x 16 pos, weights from LDS ----
    {
        const unsigned* hr   = &h1p[wv][s][0];
        const unsigned* wrow = w2p + lane * 49;   // row stride 49: conflict-free
        float sacc[16];
        #pragma unroll
        for (int l = 0; l < 16; ++l) sacc[l] = bz2;
        #pragma unroll 4
        for (int m = 0; m < 16; ++m) {
            uint4 r4[5];
            const uint4* rp = (const uint4*)(hr + m * 20);
            #pragma unroll
            for (int q = 0; q < 5; ++q) r4[q] = rp[q];        // broadcast b128
            const unsigned* rw = (const unsigned*)r4;
            const half2_t wk0 = H2(wrow[m * 3]), wk1 = H2(wrow[m * 3 + 1]), wk2 = H2(wrow[m * 3 + 2]);
            #pragma unroll
            for (int l = 0; l < 16; ++l) {
                float a = sacc[l];
                a = __builtin_amdgcn_fdot2(wk0, H2(rw[l]),     a, false);
                a = __builtin_amdgcn_fdot2(wk1, H2(rw[l + 1]), a, false);
                a = __builtin_amdgcn_fdot2(wk2, H2(rw[l + 2]), a, false);
                sacc[l] = a;
            }
        }
        float m2 = 0.0f;
        #pragma unroll
        for (int l = 0; l < 16; ++l) m2 += fmaxf(sacc[l], 0.0f);
        catb[lane] = m2 * 0.0625f;               // pf -> [0..31], tf -> [32..63]
    }
    WAVE_SYNC();    // catb visible within the wave

    // ---- projection 72 -> 64, relu (f32) ----
    {
        float acc = prb[lane];
        const float4* w4 = (const float4*)(prw + lane * 72);
        const float4* c4 = (const float4*)catb;
        #pragma unroll
        for (int q = 0; q < 18; ++q) {
            float4 w = w4[q], cv = c4[q];
            acc += w.x * cv.x + w.y * cv.y + w.z * cv.z + w.w * cv.w;
        }
        featsh[lane] = fmaxf(acc, 0.0f);
    }
    WAVE_SYNC();    // featsh visible within the wave

    // ---- xg = feat @ Wih.T + bih + bhh ; gate-blocked coalesced stores ----
    {
        float4 fr[16];
        const float4* f4 = (const float4*)featsh;
        #pragma unroll
        for (int q = 0; q < 16; ++q) fr[q] = f4[q];
        float* xgrow = xg + (size_t)bt * 256;
        #pragma unroll
        for (int gi = 0; gi < 4; ++gi) {
            const int g = gi * 64 + lane;        // torch gate order i,f,g,o
            const float4* w4 = (const float4*)(Wih + (size_t)g * 64);
            float acc = bih[g] + bhh[g];
            #pragma unroll
            for (int q = 0; q < 16; ++q) {
                float4 w = w4[q];
                acc += w.x * fr[q].x + w.y * fr[q].y + w.z * fr[q].z + w.w * fr[q].w;
            }
            xgrow[gi * 64 + lane] = acc;         // 256B contiguous per store inst
        }
    }
}

// -------------------------------------------------------------------------
// Kernel 2: LSTM — single wave per element, f16 weights + v_dot2_f32_f16
// (R9 design, absmax 0.0039). Only change: xg loads back to 4 scalar dwords
// per step (gate-blocked layout), 2-deep ring prefetch — R7-proven pattern.
// -------------------------------------------------------------------------
__global__ __launch_bounds__(64, 1) void lstm_kernel(
    const float* __restrict__ xg,     // (B,T,4,64), bias already included
    const float* __restrict__ Whh,    // (256,64)
    float* __restrict__ hout,         // (B,T,64)
    float* __restrict__ dout)         // full output buffer
{
    const int b = blockIdx.x;
    const int j = threadIdx.x;        // hidden unit index

    __shared__ __align__(16) _Float16 hs[64];    // h state in f16 (128 B)

    // 4 Whh rows for unit j (i,f,g,o) as f16 pairs: 4 x 32 uints, pinned
    unsigned wi[32], wf[32], wg[32], wo[32];
    {
        const v2f* ri = (const v2f*)(Whh + (size_t)(j)       * 64);
        const v2f* rf = (const v2f*)(Whh + (size_t)(64  + j) * 64);
        const v2f* rg = (const v2f*)(Whh + (size_t)(128 + j) * 64);
        const v2f* ro = (const v2f*)(Whh + (size_t)(192 + j) * 64);
        #pragma unroll
        for (int q = 0; q < 32; ++q) {
            v2f w;
            w = ri[q]; wi[q] = packh2(w.x, w.y);
            w = rf[q]; wf[q] = packh2(w.x, w.y);
            w = rg[q]; wg[q] = packh2(w.x, w.y);
            w = ro[q]; wo[q] = packh2(w.x, w.y);
        }
        #pragma unroll
        for (int q = 0; q < 32; ++q) { PINU(wi[q]); PINU(wf[q]); PINU(wg[q]); PINU(wo[q]); }
    }

    const float* xp = xg + (size_t)b * T_ * 256 + j;
    float* hrow = hout + (size_t)b * T_ * 64;

    float c = 0.0f;
    float h = 0.0f;
    hs[j] = (_Float16)0.0f;
    WAVE_SYNC();

    // 2-deep prefetch of the 4 per-step gate scalars
    float xc0 = xp[0],   xc1 = xp[64],  xc2 = xp[128], xc3 = xp[192];
    float xn0 = xp[256], xn1 = xp[320], xn2 = xp[384], xn3 = xp[448];

    for (int t = 0; t < T_; ++t) {
        const int tp = ((t + 2 < T_) ? (t + 2) : (T_ - 1)) * 256;
        float xf0 = xp[tp], xf1 = xp[tp + 64], xf2 = xp[tp + 128], xf3 = xp[tp + 192];

        // h broadcast: 64 halfs = 128 B = 8 x b128 reads, conflict-free
        uint4 hb[8];
        const uint4* hp = (const uint4*)hs;
        #pragma unroll
        for (int q = 0; q < 8; ++q) hb[q] = hp[q];
        const unsigned* hu = (const unsigned*)hb;

        float ai = xc0, af = xc1, ag = xc2, ao = xc3;
        #pragma unroll
        for (int q = 0; q < 32; ++q) {
            half2_t hq = H2(hu[q]);
            ai = __builtin_amdgcn_fdot2(H2(wi[q]), hq, ai, false);
            af = __builtin_amdgcn_fdot2(H2(wf[q]), hq, af, false);
            ag = __builtin_amdgcn_fdot2(H2(wg[q]), hq, ag, false);
            ao = __builtin_amdgcn_fdot2(H2(wo[q]), hq, ao, false);
        }

        const float I = sigmoidf_(ai);
        const float F = sigmoidf_(af);
        const float G = tanhf_(ag);
        const float O = sigmoidf_(ao);
        c = F * c + I * G;
        h = O * tanhf_(c);

        hs[j] = (_Float16)h;          // ds_write_b16
        WAVE_SYNC();                  // lgkmcnt only; vmem stays in flight
        hrow[t * 64 + j] = h;         // f32 coalesced store, never drained in-loop

        xc0 = xn0; xc1 = xn1; xc2 = xn2; xc3 = xn3;
        xn0 = xf0; xn1 = xf1; xn2 = xf2; xn3 = xf3;
    }

    dout[B_ * T_ * 4 + b * 64 + j]           = h;   // hT
    dout[B_ * T_ * 4 + B_ * 64 + b * 64 + j] = c;   // cT
}

// -------------------------------------------------------------------------
// Kernel 3: head (unchanged).
// -------------------------------------------------------------------------
__global__ __launch_bounds__(256) void head_kernel(
    const float* __restrict__ hout, const float* __restrict__ hw,
    const float* __restrict__ hb, float* __restrict__ out)
{
    const int blk = blockIdx.x;
    const int tid = threadIdx.x;

    __shared__ __align__(16) float hsh[64 * 68];
    __shared__ __align__(16) float wsh[256];
    __shared__ float bsh[4];

    const float4* s4 = (const float4*)(hout + (size_t)blk * 64 * 64);
    float4* d4 = (float4*)hsh;
    for (int q = tid; q < 1024; q += 256) {
        int row = q >> 4, col = q & 15;
        d4[row * 17 + col] = s4[q];
    }
    if (tid < 64) ((float4*)wsh)[tid] = ((const float4*)hw)[tid];
    if (tid < 4)  bsh[tid] = hb[tid];
    __syncthreads();

    const int r = tid >> 2, m = tid & 3;
    const float4* hv = (const float4*)(hsh + r * 68);
    const float4* wv = (const float4*)(wsh + m * 64);
    float acc = bsh[m];
    #pragma unroll
    for (int q = 0; q < 16; ++q) {
        float4 a = hv[q], w = wv[q];
        acc += a.x * w.x + a.y * w.y + a.z * w.z + a.w * w.w;
    }
    out[(size_t)blk * 256 + tid] = sigmoidf_(acc);
}

extern "C" void kernel_launch(void* const* d_in, const int* in_sizes, int n_in,
                              void* d_out, int out_size, void* d_ws, size_t ws_size,
                              hipStream_t stream) {
    const float* pressure = (const float*)d_in[0];
    const float* torque   = (const float*)d_in[1];
    const float* frag     = (const float*)d_in[2];
    const float* pw1 = (const float*)d_in[3];
    const float* pb1 = (const float*)d_in[4];
    const float* pw2 = (const float*)d_in[5];
    const float* pb2 = (const float*)d_in[6];
    const float* tw1 = (const float*)d_in[7];
    const float* tb1 = (const float*)d_in[8];
    const float* tw2 = (const float*)d_in[9];
    const float* tb2 = (const float*)d_in[10];
    const float* fw  = (const float*)d_in[11];
    const float* fb  = (const float*)d_in[12];
    const float* prw = (const float*)d_in[13];
    const float* prb = (const float*)d_in[14];
    const float* Wih = (const float*)d_in[15];
    const float* Whh = (const float*)d_in[16];
    const float* bih = (const float*)d_in[17];
    const float* bhh = (const float*)d_in[18];
    const float* hw  = (const float*)d_in[19];
    const float* hb  = (const float*)d_in[20];

    float* out = (float*)d_out;

    // workspace: xg (B*T*256 f32 = 16 MB, gate-blocked) | hout (4 MB)
    float* xg   = (float*)d_ws;
    float* hout = xg + (size_t)B_ * T_ * 256;

    encoder_kernel<<<B_ * T_ / 4, 256, 0, stream>>>(
        pressure, torque, frag,
        pw1, pb1, pw2, pb2, tw1, tb1, tw2, tb2,
        fw, fb, prw, prb, Wih, bih, bhh, xg);

    lstm_kernel<<<B_, 64, 0, stream>>>(xg, Whh, hout, out);

    head_kernel<<<B_ * T_ / 64, 256, 0, stream>>>(hout, hw, hb, out);
}

// Round 11
// 385.483 us; speedup vs baseline: 1.9372x; 1.1693x over previous
//
#include <hip/hip_runtime.h>
#include <math.h>

// Problem constants
#define B_   64
#define T_   256
#define W_   20
#define NP_  6
#define NT_  12
#define CC_  32      // CONV_CH
#define FD_  8       // FRAG_DIM
#define PR_  64      // PROJ

typedef float v2f __attribute__((ext_vector_type(2)));
typedef _Float16 half2_t __attribute__((ext_vector_type(2)));

// Pin a single 32-bit value into a VGPR (opaque def; blocks remat/spill-sink).
#define PINU(x) asm volatile("" : "+v"(x))
// Wave-local LDS ordering: drain LDS ops only; no vmcnt, no barrier.
#define WAVE_SYNC() asm volatile("s_waitcnt lgkmcnt(0)" ::: "memory")

#define H2(u) __builtin_bit_cast(half2_t, (u))

__device__ __forceinline__ unsigned packh2(float a, float b) {
    union { _Float16 h[2]; unsigned u; } cv;
    cv.h[0] = (_Float16)a; cv.h[1] = (_Float16)b;
    return cv.u;
}

// Fast activations: v_rcp_f32 instead of IEEE division (the div_scale/
// div_fmas/div_fixup sequence was ~12 serial insts x5 per LSTM step).
__device__ __forceinline__ float sigmoidf_(float x) {
    return __builtin_amdgcn_rcpf(1.0f + __expf(-x));   // -x large -> exp=inf -> rcp=0 (correct)
}
__device__ __forceinline__ float tanhf_(float x) {
    x = fminf(fmaxf(x, -15.0f), 15.0f);                // keep e finite
    float e = __expf(2.0f * x);
    return (e - 1.0f) * __builtin_amdgcn_rcpf(e + 1.0f);
}

// -------------------------------------------------------------------------
// Kernel 1: encoders + projection + LSTM input-gate precompute.
// R10 post-mortem: (256,5) forced a ~102-VGPR cap -> scratch spill
// (VGPR_Count=48, FETCH 66MB, WRITE 127MB of scratch traffic). This round:
// (256,4) = 128-VGPR budget, which the f16-dot2 code fits naturally.
// -------------------------------------------------------------------------
__global__ __launch_bounds__(256, 4) void encoder_kernel(
    const float* __restrict__ pressure, const float* __restrict__ torque,
    const float* __restrict__ frag,
    const float* __restrict__ pw1, const float* __restrict__ pb1,
    const float* __restrict__ pw2, const float* __restrict__ pb2,
    const float* __restrict__ tw1, const float* __restrict__ tb1,
    const float* __restrict__ tw2, const float* __restrict__ tb2,
    const float* __restrict__ fw,  const float* __restrict__ fb,
    const float* __restrict__ prw, const float* __restrict__ prb,
    const float* __restrict__ Wih, const float* __restrict__ bih,
    const float* __restrict__ bhh,
    float* __restrict__ xg)             // (B,T,4gates,64units) gate-blocked
{
    const int tid  = threadIdx.x;       // 0..255
    const int wv   = tid >> 6;          // wave 0..3
    const int lane = tid & 63;
    const int bt   = blockIdx.x * 4 + wv;   // window id
    const int b    = bt >> 8;
    const int  o   = lane & 31;
    const bool isp = lane < 32;
    const int  s   = isp ? 0 : 1;       // stream: 0=pressure, 1=torque

    __shared__ unsigned w2p[64 * 49];                    // 12544 B packed conv2 wts
    __shared__ __align__(16) unsigned xwp[4][2][120];    //  3840 B [wave][stream][pair*20+pos]
    __shared__ __align__(16) unsigned h1p[4][2][320];    // 10240 B
    __shared__ __align__(16) float catb4[4][72];
    __shared__ __align__(16) float featsh4[4][64];

    float* catb   = catb4[wv];
    float* featsh = featsh4[wv];

    // ---- stage conv2 weights once per block, packed f16 pairs ----
    for (int idx = tid; idx < 64 * 48; idx += 256) {
        int r = idx / 48, c = idx - r * 48;
        int m = c / 3, k = c - m * 3;
        const float* src = (r < 32) ? (pw2 + r * 96) : (tw2 + (r - 32) * 96);
        w2p[r * 49 + c] = packh2(src[(2 * m) * 3 + k], src[(2 * m + 1) * 3 + k]);
    }

    // ---- zero + stage own window as packed f16 pairs (transposed) ----
    {
        unsigned* xz = &xwp[wv][0][0];
        #pragma unroll
        for (int idx = lane; idx < 240; idx += 64) xz[idx] = 0;   // pads pressure rows 3..5
    }
    const float* pin = pressure + (size_t)bt * (W_ * NP_);
    for (int idx = lane; idx < W_ * NP_; idx += 64) {
        int w = idx / NP_, i = idx - w * NP_;
        ((_Float16*)&xwp[wv][0][(i >> 1) * 20 + w])[i & 1] = (_Float16)pin[idx];
    }
    const float* tin = torque + (size_t)bt * (W_ * NT_);
    for (int idx = lane; idx < W_ * NT_; idx += 64) {
        int w = idx / NT_, i = idx - w * NT_;
        ((_Float16*)&xwp[wv][1][(i >> 1) * 20 + w])[i & 1] = (_Float16)tin[idx];
    }
    if (lane < FD_) catb[64 + lane] = fmaxf(frag[b] * fw[lane] + fb[lane], 0.0f);

    // ---- conv1 weights: packed f16 pairs in regs, zero-padded to 6 pairs ----
    unsigned w1p[18];
    {
        const float* w1 = isp ? (pw1 + o * (NP_ * 3)) : (tw1 + o * (NT_ * 3));
        const int npr = isp ? 3 : 6;    // channel pairs
        #pragma unroll
        for (int m = 0; m < 6; ++m)
            #pragma unroll
            for (int k = 0; k < 3; ++k)
                w1p[m * 3 + k] = (m < npr)
                    ? packh2(w1[(2 * m) * 3 + k], w1[(2 * m + 1) * 3 + k])
                    : 0u;
    }
    const float bz1 = isp ? pb1[o] : tb1[o];
    const float bz2 = isp ? pb2[o] : tb2[o];
    WAVE_SYNC();    // xwp visible within the wave

    // ---- conv1: 6 pair-rows x 3 taps x 18 pos, dot2 f16 -> f32 acc ----
    {
        const unsigned* xr = &xwp[wv][s][0];
        float acc[18];
        #pragma unroll
        for (int l = 0; l < 18; ++l) acc[l] = bz1;
        #pragma unroll
        for (int m = 0; m < 6; ++m) {
            uint4 r4[5];
            const uint4* rp = (const uint4*)(xr + m * 20);
            #pragma unroll
            for (int q = 0; q < 5; ++q) r4[q] = rp[q];        // broadcast b128
            const unsigned* rw = (const unsigned*)r4;
            const half2_t wk0 = H2(w1p[m * 3]), wk1 = H2(w1p[m * 3 + 1]), wk2 = H2(w1p[m * 3 + 2]);
            #pragma unroll
            for (int l = 0; l < 18; ++l) {
                float a = acc[l];
                a = __builtin_amdgcn_fdot2(wk0, H2(rw[l]),     a, false);
                a = __builtin_amdgcn_fdot2(wk1, H2(rw[l + 1]), a, false);
                a = __builtin_amdgcn_fdot2(wk2, H2(rw[l + 2]), a, false);
                acc[l] = a;
            }
        }
        #pragma unroll
        for (int l = 0; l < 18; ++l)
            ((_Float16*)&h1p[wv][s][(o >> 1) * 20 + l])[o & 1] = (_Float16)fmaxf(acc[l], 0.0f);
    }
    __syncthreads();   // the ONE real barrier: w2p (cross-wave) + h1p ready

    // ---- conv2: 16 pair-rows x 3 taps x 16 pos, weights from LDS ----
    {
        const unsigned* hr   = &h1p[wv][s][0];
        const unsigned* wrow = w2p + lane * 49;   // row stride 49: conflict-free
        float sacc[16];
        #pragma unroll
        for (int l = 0; l < 16; ++l) sacc[l] = bz2;
        #pragma unroll 4
        for (int m = 0; m < 16; ++m) {
            uint4 r4[5];
            const uint4* rp = (const uint4*)(hr + m * 20);
            #pragma unroll
            for (int q = 0; q < 5; ++q) r4[q] = rp[q];        // broadcast b128
            const unsigned* rw = (const unsigned*)r4;
            const half2_t wk0 = H2(wrow[m * 3]), wk1 = H2(wrow[m * 3 + 1]), wk2 = H2(wrow[m * 3 + 2]);
            #pragma unroll
            for (int l = 0; l < 16; ++l) {
                float a = sacc[l];
                a = __builtin_amdgcn_fdot2(wk0, H2(rw[l]),     a, false);
                a = __builtin_amdgcn_fdot2(wk1, H2(rw[l + 1]), a, false);
                a = __builtin_amdgcn_fdot2(wk2, H2(rw[l + 2]), a, false);
                sacc[l] = a;
            }
        }
        float m2 = 0.0f;
        #pragma unroll
        for (int l = 0; l < 16; ++l) m2 += fmaxf(sacc[l], 0.0f);
        catb[lane] = m2 * 0.0625f;               // pf -> [0..31], tf -> [32..63]
    }
    WAVE_SYNC();    // catb visible within the wave

    // ---- projection 72 -> 64, relu (f32) ----
    {
        float acc = prb[lane];
        const float4* w4 = (const float4*)(prw + lane * 72);
        const float4* c4 = (const float4*)catb;
        #pragma unroll
        for (int q = 0; q < 18; ++q) {
            float4 w = w4[q], cv = c4[q];
            acc += w.x * cv.x + w.y * cv.y + w.z * cv.z + w.w * cv.w;
        }
        featsh[lane] = fmaxf(acc, 0.0f);
    }
    WAVE_SYNC();    // featsh visible within the wave

    // ---- xg = feat @ Wih.T + bih + bhh ; gate-blocked coalesced stores ----
    {
        float4 fr[16];
        const float4* f4 = (const float4*)featsh;
        #pragma unroll
        for (int q = 0; q < 16; ++q) fr[q] = f4[q];
        float* xgrow = xg + (size_t)bt * 256;
        #pragma unroll
        for (int gi = 0; gi < 4; ++gi) {
            const int g = gi * 64 + lane;        // torch gate order i,f,g,o
            const float4* w4 = (const float4*)(Wih + (size_t)g * 64);
            float acc = bih[g] + bhh[g];
            #pragma unroll
            for (int q = 0; q < 16; ++q) {
                float4 w = w4[q];
                acc += w.x * fr[q].x + w.y * fr[q].y + w.z * fr[q].z + w.w * fr[q].w;
            }
            xgrow[gi * 64 + lane] = acc;         // 256B contiguous per store inst
        }
    }
}

// -------------------------------------------------------------------------
// Kernel 2: LSTM — single wave per element, f16 weights + v_dot2_f32_f16.
// This round: (a) rcp-based activations (was: 5 IEEE-div sequences/step on
// the serial chain), (b) h stored to global as ONE float4 per 4 steps
// (tq-grouped layout (B,T/4,64,4)) -> 4x fewer vmem queue entries.
// -------------------------------------------------------------------------
__global__ __launch_bounds__(64, 1) void lstm_kernel(
    const float* __restrict__ xg,     // (B,T,4,64), bias already included
    const float* __restrict__ Whh,    // (256,64)
    float* __restrict__ hout,         // (B, T/4, 64units, 4t)
    float* __restrict__ dout)         // full output buffer
{
    const int b = blockIdx.x;
    const int j = threadIdx.x;        // hidden unit index

    __shared__ __align__(16) _Float16 hs[64];    // h state in f16 (128 B)

    // 4 Whh rows for unit j (i,f,g,o) as f16 pairs: 4 x 32 uints, pinned
    unsigned wi[32], wf[32], wg[32], wo[32];
    {
        const v2f* ri = (const v2f*)(Whh + (size_t)(j)       * 64);
        const v2f* rf = (const v2f*)(Whh + (size_t)(64  + j) * 64);
        const v2f* rg = (const v2f*)(Whh + (size_t)(128 + j) * 64);
        const v2f* ro = (const v2f*)(Whh + (size_t)(192 + j) * 64);
        #pragma unroll
        for (int q = 0; q < 32; ++q) {
            v2f w;
            w = ri[q]; wi[q] = packh2(w.x, w.y);
            w = rf[q]; wf[q] = packh2(w.x, w.y);
            w = rg[q]; wg[q] = packh2(w.x, w.y);
            w = ro[q]; wo[q] = packh2(w.x, w.y);
        }
        #pragma unroll
        for (int q = 0; q < 32; ++q) { PINU(wi[q]); PINU(wf[q]); PINU(wg[q]); PINU(wo[q]); }
    }

    const float* xp = xg + (size_t)b * T_ * 256 + j;
    float4* hq4 = (float4*)(hout + (size_t)b * T_ * 64);   // + tq*64 + j (float4 units)

    float c = 0.0f;
    float h = 0.0f;
    hs[j] = (_Float16)0.0f;
    WAVE_SYNC();

    // 2-deep prefetch of the 4 per-step gate scalars
    float xc0 = xp[0],   xc1 = xp[64],  xc2 = xp[128], xc3 = xp[192];
    float xn0 = xp[256], xn1 = xp[320], xn2 = xp[384], xn3 = xp[448];

    for (int tq = 0; tq < T_ / 4; ++tq) {
        float4 hacc;
        #pragma unroll
        for (int k = 0; k < 4; ++k) {
            const int t = tq * 4 + k;
            const int tp = ((t + 2 < T_) ? (t + 2) : (T_ - 1)) * 256;
            float xf0 = xp[tp], xf1 = xp[tp + 64], xf2 = xp[tp + 128], xf3 = xp[tp + 192];

            // h broadcast: 64 halfs = 128 B = 8 x b128 reads, conflict-free
            uint4 hb[8];
            const uint4* hp = (const uint4*)hs;
            #pragma unroll
            for (int q = 0; q < 8; ++q) hb[q] = hp[q];
            const unsigned* hu = (const unsigned*)hb;

            float ai = xc0, af = xc1, ag = xc2, ao = xc3;
            #pragma unroll
            for (int q = 0; q < 32; ++q) {
                half2_t hq = H2(hu[q]);
                ai = __builtin_amdgcn_fdot2(H2(wi[q]), hq, ai, false);
                af = __builtin_amdgcn_fdot2(H2(wf[q]), hq, af, false);
                ag = __builtin_amdgcn_fdot2(H2(wg[q]), hq, ag, false);
                ao = __builtin_amdgcn_fdot2(H2(wo[q]), hq, ao, false);
            }

            const float I = sigmoidf_(ai);
            const float F = sigmoidf_(af);
            const float G = tanhf_(ag);
            const float O = sigmoidf_(ao);
            c = F * c + I * G;
            h = O * tanhf_(c);

            hs[j] = (_Float16)h;      // ds_write_b16
            WAVE_SYNC();              // lgkmcnt only; vmem stays in flight
            (&hacc.x)[k] = h;         // static index (unrolled)

            xc0 = xn0; xc1 = xn1; xc2 = xn2; xc3 = xn3;
            xn0 = xf0; xn1 = xf1; xn2 = xf2; xn3 = xf3;
        }
        hq4[tq * 64 + j] = hacc;      // 16B/lane, 1KB/wave, once per 4 steps
    }

    dout[B_ * T_ * 4 + b * 64 + j]           = h;   // hT
    dout[B_ * T_ * 4 + B_ * 64 + b * 64 + j] = c;   // cT
}

// -------------------------------------------------------------------------
// Kernel 3: head — adapted to the tq-grouped hout layout (B,T/4,64,4).
// Global span per block is unchanged (fully coalesced float4 reads); the
// remap into the LDS [t][unit] tile happens on the LDS-write side.
// -------------------------------------------------------------------------
__global__ __launch_bounds__(256) void head_kernel(
    const float* __restrict__ hout, const float* __restrict__ hw,
    const float* __restrict__ hb, float* __restrict__ out)
{
    const int blk = blockIdx.x;
    const int tid = threadIdx.x;

    __shared__ __align__(16) float hsh[64 * 68];   // [t_local][unit], row stride 68
    __shared__ __align__(16) float wsh[256];
    __shared__ float bsh[4];

    const float4* s4 = (const float4*)(hout + (size_t)blk * 64 * 64);
    for (int q = tid; q < 1024; q += 256) {
        int tqL = q >> 6;             // local tq group 0..15
        int j   = q & 63;             // unit
        float4 v = s4[q];             // h[j] for t = tqL*4 .. tqL*4+3
        #pragma unroll
        for (int k = 0; k < 4; ++k)
            hsh[(tqL * 4 + k) * 68 + j] = (&v.x)[k];   // consecutive banks per lane
    }
    if (tid < 64) ((float4*)wsh)[tid] = ((const float4*)hw)[tid];
    if (tid < 4)  bsh[tid] = hb[tid];
    __syncthreads();

    const int r = tid >> 2, m = tid & 3;
    const float4* hv = (const float4*)(hsh + r * 68);
    const float4* wv = (const float4*)(wsh + m * 64);
    float acc = bsh[m];
    #pragma unroll
    for (int q = 0; q < 16; ++q) {
        float4 a = hv[q], w = wv[q];
        acc += a.x * w.x + a.y * w.y + a.z * w.z + a.w * w.w;
    }
    out[(size_t)blk * 256 + tid] = sigmoidf_(acc);
}

extern "C" void kernel_launch(void* const* d_in, const int* in_sizes, int n_in,
                              void* d_out, int out_size, void* d_ws, size_t ws_size,
                              hipStream_t stream) {
    const float* pressure = (const float*)d_in[0];
    const float* torque   = (const float*)d_in[1];
    const float* frag     = (const float*)d_in[2];
    const float* pw1 = (const float*)d_in[3];
    const float* pb1 = (const float*)d_in[4];
    const float* pw2 = (const float*)d_in[5];
    const float* pb2 = (const float*)d_in[6];
    const float* tw1 = (const float*)d_in[7];
    const float* tb1 = (const float*)d_in[8];
    const float* tw2 = (const float*)d_in[9];
    const float* tb2 = (const float*)d_in[10];
    const float* fw  = (const float*)d_in[11];
    const float* fb  = (const float*)d_in[12];
    const float* prw = (const float*)d_in[13];
    const float* prb = (const float*)d_in[14];
    const float* Wih = (const float*)d_in[15];
    const float* Whh = (const float*)d_in[16];
    const float* bih = (const float*)d_in[17];
    const float* bhh = (const float*)d_in[18];
    const float* hw  = (const float*)d_in[19];
    const float* hb  = (const float*)d_in[20];

    float* out = (float*)d_out;

    // workspace: xg (B*T*256 f32 = 16 MB, gate-blocked) | hout (4 MB, tq-grouped)
    float* xg   = (float*)d_ws;
    float* hout = xg + (size_t)B_ * T_ * 256;

    encoder_kernel<<<B_ * T_ / 4, 256, 0, stream>>>(
        pressure, torque, frag,
        pw1, pb1, pw2, pb2, tw1, tb1, tw2, tb2,
        fw, fb, prw, prb, Wih, bih, bhh, xg);

    lstm_kernel<<<B_, 64, 0, stream>>>(xg, Whh, hout, out);

    head_kernel<<<B_ * T_ / 64, 256, 0, stream>>>(hout, hw, hb, out);
}